// Round 1
// baseline (128.441 us; speedup 1.0000x reference)
//
#include <hip/hip_runtime.h>
#include <math.h>

#define BB 4
#define CC 32
#define HH 128
#define WW 128

// ---------------------------------------------------------------------------
// Kernel 1: fused maxpool: x (B,C,128,128) -> p1 (B,C,64,64), p2 (B,C,32,32)
// One thread per p2 element; reads a 4x4 patch as 4x float4 (coalesced 16B).
// ---------------------------------------------------------------------------
__global__ __launch_bounds__(256) void pool_kernel(const float* __restrict__ x,
                                                   float* __restrict__ p1,
                                                   float* __restrict__ p2) {
  int idx = blockIdx.x * 256 + threadIdx.x;          // B*C*32*32 = 131072
  int j  = idx & 31;
  int i  = (idx >> 5) & 31;
  int bc = idx >> 10;                                 // b*C + c
  const float* xp = x + ((size_t)bc * HH + 4 * i) * WW + 4 * j;
  float4 r0 = *(const float4*)(xp);
  float4 r1 = *(const float4*)(xp + WW);
  float4 r2 = *(const float4*)(xp + 2 * WW);
  float4 r3 = *(const float4*)(xp + 3 * WW);
  float m00 = fmaxf(fmaxf(r0.x, r1.x), fmaxf(r0.y, r1.y));
  float m01 = fmaxf(fmaxf(r0.z, r1.z), fmaxf(r0.w, r1.w));
  float m10 = fmaxf(fmaxf(r2.x, r3.x), fmaxf(r2.y, r3.y));
  float m11 = fmaxf(fmaxf(r2.z, r3.z), fmaxf(r2.w, r3.w));
  float* pp = p1 + ((size_t)bc * 64 + 2 * i) * 64 + 2 * j;
  pp[0]  = m00; pp[1]  = m01;
  pp[64] = m10; pp[65] = m11;
  p2[(size_t)bc * 1024 + i * 32 + j] = fmaxf(fmaxf(m00, m01), fmaxf(m10, m11));
}

// ---------------------------------------------------------------------------
// Kernels 2-4: depthwise 3x3, stride 1, pad 1 (cross-correlation, like lax.conv)
// One thread per output pixel. WSH/HSH = log2 of spatial dims.
// ---------------------------------------------------------------------------
template <int HS, int WS, int HSH, int WSH>
__global__ __launch_bounds__(256) void dwconv_kernel(const float* __restrict__ in,
                                                     const float* __restrict__ wt,
                                                     const float* __restrict__ bias,
                                                     float* __restrict__ out) {
  int idx = blockIdx.x * 256 + threadIdx.x;
  int w_ = idx & (WS - 1);
  int h_ = (idx >> WSH) & (HS - 1);
  int bc = idx >> (WSH + HSH);
  int c  = bc & (CC - 1);
  const float* ip = in + (size_t)bc * (HS * WS);
  float wv[9];
#pragma unroll
  for (int t = 0; t < 9; ++t) wv[t] = wt[c * 9 + t];
  float acc = bias[c];
#pragma unroll
  for (int dh = 0; dh < 3; ++dh) {
    int hh = h_ + dh - 1;
    if ((unsigned)hh >= (unsigned)HS) continue;
#pragma unroll
    for (int dw = 0; dw < 3; ++dw) {
      int ww = w_ + dw - 1;
      if ((unsigned)ww >= (unsigned)WS) continue;
      acc = fmaf(wv[dh * 3 + dw], ip[hh * WS + ww], acc);
    }
  }
  out[idx] = acc;
}

// ---------------------------------------------------------------------------
// Kernel 5: per-pixel softmax channel mixing + 1x1 conv + exact GELU + mul x.
//   q = s0[pixel,:], k = c1[h/2,w/2,:], v = c2[h/4,w/4,:]
//   qkv[i] = sum_j q[j] * exp(v[i]k[j]) / sum_i' exp(v[i']k[j])
//   out    = gelu(wa @ qkv + ba) * x
// One thread per pixel. max_i v[i]k[j] computed as k[j]*(k>=0?vmax:vmin).
// wa/ba reads are wave-uniform -> scalar s_loads (no LDS pressure).
// ---------------------------------------------------------------------------
__global__ __launch_bounds__(256) void mix_kernel(const float* __restrict__ s0,
                                                  const float* __restrict__ c1,
                                                  const float* __restrict__ c2,
                                                  const float* __restrict__ x,
                                                  const float* __restrict__ wa,
                                                  const float* __restrict__ ba,
                                                  float* __restrict__ out) {
  int n  = blockIdx.x * 256 + threadIdx.x;            // 65536 pixels
  int w_ = n & (WW - 1);
  int h_ = (n >> 7) & (HH - 1);
  int b  = n >> 14;
  size_t base0 = ((size_t)(b * CC) * HH + h_) * WW + w_;            // +c*16384
  size_t base1 = ((size_t)(b * CC) * 64 + (h_ >> 1)) * 64 + (w_ >> 1); // +c*4096
  size_t base2 = ((size_t)(b * CC) * 32 + (h_ >> 2)) * 32 + (w_ >> 2); // +c*1024

  float v[CC], e[CC], qkv[CC];
#pragma unroll
  for (int i = 0; i < CC; ++i) {
    v[i]   = c2[base2 + i * 1024];
    qkv[i] = 0.f;
  }
  float vmax = v[0], vmin = v[0];
#pragma unroll
  for (int i = 1; i < CC; ++i) {
    vmax = fmaxf(vmax, v[i]);
    vmin = fminf(vmin, v[i]);
  }

  const float L2E = 1.4426950408889634f;
  float kj = c1[base1];
  float qj = s0[base0];
  for (int j = 0; j < CC; ++j) {
    float kjn = 0.f, qjn = 0.f;
    if (j + 1 < CC) {                      // software prefetch next j
      kjn = c1[base1 + (size_t)(j + 1) * 4096];
      qjn = s0[base0 + (size_t)(j + 1) * 16384];
    }
    float m  = (kj >= 0.f) ? kj * vmax : kj * vmin;   // max_i v[i]*kj
    float kl = kj * L2E;
    float nm = -m * L2E;
    float d0 = 0.f, d1 = 0.f, d2 = 0.f, d3 = 0.f;
#pragma unroll
    for (int i = 0; i < CC; i += 4) {
      e[i]     = __builtin_amdgcn_exp2f(fmaf(v[i],     kl, nm)); d0 += e[i];
      e[i + 1] = __builtin_amdgcn_exp2f(fmaf(v[i + 1], kl, nm)); d1 += e[i + 1];
      e[i + 2] = __builtin_amdgcn_exp2f(fmaf(v[i + 2], kl, nm)); d2 += e[i + 2];
      e[i + 3] = __builtin_amdgcn_exp2f(fmaf(v[i + 3], kl, nm)); d3 += e[i + 3];
    }
    float denom = (d0 + d1) + (d2 + d3);
    float scale = __fdividef(qj, denom);
#pragma unroll
    for (int i = 0; i < CC; ++i) qkv[i] = fmaf(scale, e[i], qkv[i]);
    kj = kjn;
    qj = qjn;
  }

  // 1x1 conv (wa uniform -> scalar loads) + exact GELU + elementwise * x
  for (int o = 0; o < CC; ++o) {
    float y = ba[o];
#pragma unroll
    for (int c2i = 0; c2i < CC; ++c2i) y = fmaf(wa[o * CC + c2i], qkv[c2i], y);
    float g = 0.5f * y * (1.f + erff(y * 0.70710678118654752f));
    size_t oi = base0 + (size_t)o * (HH * WW);
    out[oi] = g * x[oi];
  }
}

// ---------------------------------------------------------------------------
extern "C" void kernel_launch(void* const* d_in, const int* in_sizes, int n_in,
                              void* d_out, int out_size, void* d_ws, size_t ws_size,
                              hipStream_t stream) {
  const float* x  = (const float*)d_in[0];
  const float* w0 = (const float*)d_in[1];
  const float* b0 = (const float*)d_in[2];
  const float* w1 = (const float*)d_in[3];
  const float* b1 = (const float*)d_in[4];
  const float* w2 = (const float*)d_in[5];
  const float* b2 = (const float*)d_in[6];
  const float* wa = (const float*)d_in[7];
  const float* ba = (const float*)d_in[8];
  float* out = (float*)d_out;

  float* ws = (float*)d_ws;
  float* s0 = ws;                    // B*C*128*128 = 2097152 floats
  float* p1 = s0 + 2097152;          // B*C*64*64   =  524288
  float* c1 = p1 + 524288;           //              524288
  float* p2 = c1 + 524288;           // B*C*32*32   =  131072
  float* c2 = p2 + 131072;           //              131072
  // total 3.4M floats = 13 MB of workspace

  pool_kernel<<<512, 256, 0, stream>>>(x, p1, p2);
  dwconv_kernel<128, 128, 7, 7><<<8192, 256, 0, stream>>>(x, w0, b0, s0);
  dwconv_kernel<64, 64, 6, 6><<<2048, 256, 0, stream>>>(p1, w1, b1, c1);
  dwconv_kernel<32, 32, 5, 5><<<512, 256, 0, stream>>>(p2, w2, b2, c2);
  mix_kernel<<<256, 256, 0, stream>>>(s0, c1, c2, x, wa, ba, out);
}